// Round 8
// baseline (154.486 us; speedup 1.0000x reference)
//
#include <hip/hip_runtime.h>
#include <cstdint>
#include <cstddef>

// ---------------------------------------------------------------------------
// DeMash = complex GEMM: out[bts, m] = sum_l y[bts, l] * conj(C)[m, l]
//   out_r = Yr@Cr^T + Yi@Ci^T ; out_i = Yi@Cr^T - Yr@Ci^T
// One real NT GEMM:
//   A [M=2048, K=3072] row-major fp16  (K: [Yr(1512) | Yi(1512) | 0-pad])
//   W [N=3072, K=3072] row-major fp16  (n<1512: [Cr|Ci|0]; 1512..3023:
//                                       [-Ci|Cr|0]; rest 0)
//   Out[m, n] = sum_k A[m,k] * W[n,k] -> scattered into [2,2048,14,128]
//
// R8: gemm FETCH_SIZE 58.4MB vs 31.5MB ideal (1.85x L2-miss overfetch) and
// the dominant stall is the barrier drain of staging loads -> cut their miss
// latency with an XCD-aware swizzle: block b -> xcd=b%8 owns bn in
// {3*xcd..3*xcd+2} x all bm (bm-major). Per-XCD W working set = 2.36MB,
// L2-resident; W fetched from HBM once. GEMM body = R3/R7 verbatim
// (64x128, BK=64, XOR swizzle, 2-barrier single-buffer — R5 dbuf and R6
// 128-tile both measured regressions). Prep = R7's coalesced version.
// ---------------------------------------------------------------------------

typedef _Float16 half_t;
typedef half_t half8 __attribute__((ext_vector_type(8)));
typedef half_t half4 __attribute__((ext_vector_type(4)));
typedef half_t half2_t __attribute__((ext_vector_type(2)));
typedef float floatx4 __attribute__((ext_vector_type(4)));
typedef float floatv4 __attribute__((ext_vector_type(4)));

#define M_DIM 2048
#define N_DIM 3072
#define K_DIM 3072
#define LDIM 1512
#define NSC 108
#define SYMS 14
#define FFT 128
#define ROWLEN (SYMS * FFT)   // 1792

#define BM 64
#define BN 128
#define BK 64
#define NITER (K_DIM / BK)    // 48

// prep grid partition (blocks of 256 threads)
#define PA2_BLOCKS 6048   // A: 2048 rows x 14 syms x 54 j-pairs / 256
#define PW2_BLOCKS 9072   // W: 3072 rows x 756 k-quads / 256
#define PAP_BLOCKS 48     // A k-pad zero: 2048 x 48 halves / 8 / 256
#define PG_BLOCKS 4480    // guard zero: 2*2048*14*20 / 256
#define PREP_BLOCKS (PA2_BLOCKS + PW2_BLOCKS + PAP_BLOCKS + PG_BLOCKS)

typedef __attribute__((address_space(3))) uint32_t lds_u32_t;
typedef const __attribute__((address_space(1))) uint32_t glob_u32_t;

__device__ __forceinline__ void gl2lds16(const void* g, void* l) {
    __builtin_amdgcn_global_load_lds((glob_u32_t*)g, (lds_u32_t*)l, 16, 0, 0);
}

// ---------------------------------------------------------------------------
// prep_all (one dispatch, 4 regions, wave-uniform region branch):
//  [0, PA2): A-build, coalesced (lanes walk subcarrier pairs).
//  [PA2, +PW2): W-build, float4 loads contiguous across lanes.
//  then A k-pad zeros, then output guard-column zeros.   (R7, proven)
// ---------------------------------------------------------------------------
__global__ __launch_bounds__(256) void prep_all(
    const float* __restrict__ xr, const float* __restrict__ xi,
    const float* __restrict__ Cr, const float* __restrict__ Ci,
    const int* __restrict__ sc,
    half_t* __restrict__ A, half_t* __restrict__ W, float* __restrict__ out)
{
    const int b = blockIdx.x;
    const int t = threadIdx.x;

    if (b < PA2_BLOCKS) {
        int idx = b * 256 + t;          // [0, 2048*14*54)
        int jp = idx % 54;
        int rest = idx / 54;
        int sym = rest % 14;
        int row = rest / 14;
        int s0 = sc[2 * jp];
        int s1 = sc[2 * jp + 1];
        const float* xrp = xr + (size_t)row * ROWLEN + sym * FFT;
        const float* xip = xi + (size_t)row * ROWLEN + sym * FFT;
        half2_t hr = { (half_t)xrp[s0], (half_t)xrp[s1] };
        half2_t hi = { (half_t)xip[s0], (half_t)xip[s1] };
        size_t dst = (size_t)row * K_DIM + sym * NSC + 2 * jp;
        *(half2_t*)(A + dst) = hr;
        *(half2_t*)(A + dst + LDIM) = hi;
    } else if (b < PA2_BLOCKS + PW2_BLOCKS) {
        int idx = (b - PA2_BLOCKS) * 256 + t;   // [0, 3072*756)
        int kq = idx % 756;
        int n = idx / 756;
        int k0 = kq * 4;
        floatv4 f = {0.0f, 0.0f, 0.0f, 0.0f};
        if (n < LDIM) {
            if (k0 < LDIM)
                f = *(const floatv4*)(Cr + (size_t)n * LDIM + k0);
            else
                f = *(const floatv4*)(Ci + (size_t)n * LDIM + (k0 - LDIM));
        } else if (n < 2 * LDIM) {
            int m = n - LDIM;
            if (k0 < LDIM) {
                f = *(const floatv4*)(Ci + (size_t)m * LDIM + k0);
                f = -f;
            } else {
                f = *(const floatv4*)(Cr + (size_t)m * LDIM + (k0 - LDIM));
            }
        }
        half4 h = { (half_t)f.x, (half_t)f.y, (half_t)f.z, (half_t)f.w };
        *(half4*)(W + (size_t)n * K_DIM + k0) = h;
    } else if (b < PA2_BLOCKS + PW2_BLOCKS + PAP_BLOCKS) {
        int idx = (b - PA2_BLOCKS - PW2_BLOCKS) * 256 + t;  // [0, 12288)
        int c = idx % 6;
        int row = idx / 6;
        half8 z = {};
        *(half8*)(A + (size_t)row * K_DIM + 2 * LDIM + c * 8) = z;
    } else {
        // zero guard columns [0,10) U [118,128) for all 4096 rows x 14 syms
        int idx = (b - PA2_BLOCKS - PW2_BLOCKS - PAP_BLOCKS) * 256 + t;
        int c20 = idx % 20;
        int rest = idx / 20;
        int sym = rest % 14;
        int rowri = rest / 14;                 // [0, 4096) covers both ri
        int col = (c20 < 10) ? c20 : (NSC + c20);
        out[(size_t)rowri * ROWLEN + sym * FFT + col] = 0.0f;
    }
}

// ---------------------------------------------------------------------------
// gemm_scatter: 64x128 tile, BK=64, single-buffered (24 KB), 4 waves each
// 64Mx32N via 4x2 mfma_f32_16x16x32_f16 x 2 k-steps. grid 768 (1-D),
// XCD-aware swizzle: xcd = blk%8 -> bn in {3*xcd..3*xcd+2}, bm-major so
// 3 consecutive blocks share the A-tile. XOR bank swizzle (conflicts = 0).
// ---------------------------------------------------------------------------
__global__ __launch_bounds__(256) void gemm_scatter(
    const half_t* __restrict__ A,   // [M_DIM][K_DIM]
    const half_t* __restrict__ W,   // [N_DIM][K_DIM]
    const int* __restrict__ sc,
    float* __restrict__ out)        // [2][2048][14][128]; guards pre-zeroed
{
    __shared__ __align__(16) half_t As[BM * BK];   // 8 KB
    __shared__ __align__(16) half_t Bs[BN * BK];   // 16 KB

    const int t = threadIdx.x;

    // XCD-aware block swizzle (dispatch round-robins blocks over 8 XCDs):
    // xcd owns bn in {3*xcd .. 3*xcd+2} for all 32 bm -> per-XCD W working
    // set = 3 x 786KB = 2.36MB, fits the 4MB per-XCD L2.
    const int blk = blockIdx.x;
    const int xcd = blk & 7;
    const int j = blk >> 3;          // [0, 96)
    const int bn = xcd * 3 + (j % 3);
    const int bm = j / 3;

    const int lane = t & 63;
    const int wn = (t >> 6) * 32;     // wave's N offset in tile

    floatx4 acc[4][2] = {};

    // staging: chunk c (16B): row = c>>3, slot = c&7, global k-chunk
    // g = slot ^ (row&7). LDS dest = base + c*16 (contiguous per lane).
    const half_t* gAp[2];
    const half_t* gBp[4];
    half_t* lAp[2];
    half_t* lBp[4];
#pragma unroll
    for (int r = 0; r < 2; ++r) {
        int c = r * 256 + t;
        int row = c >> 3, slot = c & 7;
        int g = slot ^ (row & 7);
        gAp[r] = A + (size_t)(bm * BM + row) * K_DIM + g * 8;
        lAp[r] = As + c * 8;
    }
#pragma unroll
    for (int r = 0; r < 4; ++r) {
        int c = r * 256 + t;
        int row = c >> 3, slot = c & 7;
        int g = slot ^ (row & 7);
        gBp[r] = W + (size_t)(bn * BN + row) * K_DIM + g * 8;
        lBp[r] = Bs + c * 8;
    }

    const int fr = lane & 15;         // fragment row (M or N within 16)
    const int cr = lane >> 4;         // k-quad index within a 32-k step
    const int slot0 = (cr) ^ (fr & 7);
    const int slot1 = (4 + cr) ^ (fr & 7);

    for (int kb = 0; kb < NITER; ++kb) {
        __syncthreads();
        gl2lds16(gAp[0], lAp[0]);
        gl2lds16(gAp[1], lAp[1]);
        gl2lds16(gBp[0], lBp[0]);
        gl2lds16(gBp[1], lBp[1]);
        gl2lds16(gBp[2], lBp[2]);
        gl2lds16(gBp[3], lBp[3]);
        gAp[0] += BK; gAp[1] += BK;
        gBp[0] += BK; gBp[1] += BK; gBp[2] += BK; gBp[3] += BK;
        __syncthreads();

        half8 af[2][4], bf[2][2];
#pragma unroll
        for (int i = 0; i < 4; ++i) {
            int rbase = (i * 16 + fr) * BK;
            af[0][i] = *(const half8*)&As[rbase + slot0 * 8];
            af[1][i] = *(const half8*)&As[rbase + slot1 * 8];
        }
#pragma unroll
        for (int j2 = 0; j2 < 2; ++j2) {
            int rbase = (wn + j2 * 16 + fr) * BK;
            bf[0][j2] = *(const half8*)&Bs[rbase + slot0 * 8];
            bf[1][j2] = *(const half8*)&Bs[rbase + slot1 * 8];
        }
#pragma unroll
        for (int s = 0; s < 2; ++s)
#pragma unroll
            for (int i = 0; i < 4; ++i)
#pragma unroll
                for (int j2 = 0; j2 < 2; ++j2)
                    acc[i][j2] = __builtin_amdgcn_mfma_f32_16x16x32_f16(
                        af[s][i], bf[s][j2], acc[i][j2], 0, 0, 0);
    }

    // epilogue: C/D layout col = lane&15 (N), row = (lane>>4)*4 + reg (M)
    const int col_base = bn * BN + wn + (lane & 15);
    const int row_base = bm * BM + ((lane >> 4) * 4);
#pragma unroll
    for (int j2 = 0; j2 < 2; ++j2) {
        int n = col_base + j2 * 16;
        if (n >= 2 * LDIM) continue;           // N-pad region: discard
        int ri = (n >= LDIM) ? 1 : 0;
        int nn = n - ri * LDIM;
        int sym = nn / NSC;
        int jj = nn - sym * NSC;
        size_t colOff = (size_t)ri * (M_DIM * ROWLEN) + sym * FFT + sc[jj];
#pragma unroll
        for (int i = 0; i < 4; ++i) {
            int row0 = row_base + i * 16;
#pragma unroll
            for (int r = 0; r < 4; ++r) {
                out[colOff + (size_t)(row0 + r) * ROWLEN] = acc[i][j2][r];
            }
        }
    }
}

// ---------------------------------------------------------------------------
extern "C" void kernel_launch(void* const* d_in, const int* in_sizes, int n_in,
                              void* d_out, int out_size, void* d_ws, size_t ws_size,
                              hipStream_t stream) {
    const float* xr = (const float*)d_in[0];
    const float* xi = (const float*)d_in[1];
    const float* Cr = (const float*)d_in[2];
    const float* Ci = (const float*)d_in[3];
    const int* sc   = (const int*)d_in[4];
    float* out = (float*)d_out;

    half_t* Ah = (half_t*)d_ws;                                      // 12.58 MB
    half_t* Wh = (half_t*)((char*)d_ws + (size_t)M_DIM * K_DIM * 2); // 18.87 MB

    prep_all<<<PREP_BLOCKS, 256, 0, stream>>>(
        xr, xi, Cr, Ci, sc, Ah, Wh, out);

    gemm_scatter<<<768, 256, 0, stream>>>(Ah, Wh, sc, out);
}